// Round 14
// baseline (56.113 us; speedup 1.0000x reference)
//
#include <hip/hip_runtime.h>

#define N_TOT  524288
#define NN1    524289
#define PP     8
#define AA     65536
#define SEGLEN 64
#define NSEG   8193      /* ceil(NN1/64) */
#define CHUNK  64        /* segments per chunk (full wave) */
#define NCHK   129       /* ceil(NSEG/64) */
#define NE     (NCHK*4)  /* 516 link slots */

/* workspace offsets, in floats (all float4-aligned) */
#define OFF_POS  0            /* float4[524288] = 2097152 floats */
#define OFF_NT   2097152      /* float4[NN1]    = 2097156 floats */
#define OFF_L1G  4194308      /* NSEG*48 = 393264 */
#define OFF_L1E  4587572      /* NSEG*4 ints */
#define OFF_PREG 4620344      /* NSEG*48 */
#define OFF_PREE 5013608      /* NSEG*4 ints */
#define OFF_CLG  5046380      /* NE*12 = 6192 */
#define OFF_CLE  5052572      /* NE ints (516) */
#define OFF_KINV 5053088      /* N_TOT ints */

static __device__ __forceinline__ void set_ident(float* a){
  a[0]=1.f;a[1]=0.f;a[2]=0.f;a[3]=0.f;
  a[4]=0.f;a[5]=1.f;a[6]=0.f;a[7]=0.f;
  a[8]=0.f;a[9]=0.f;a[10]=1.f;a[11]=0.f;
}

/* O = A @ B (3x4 affine, row-major) */
static __device__ __forceinline__ void compose(const float* Aa, const float* B, float* O){
  #pragma unroll
  for(int r=0;r<3;r++){
    float a0=Aa[r*4+0],a1=Aa[r*4+1],a2=Aa[r*4+2],a3=Aa[r*4+3];
    O[r*4+0]=a0*B[0]+a1*B[4]+a2*B[8];
    O[r*4+1]=a0*B[1]+a1*B[5]+a2*B[9];
    O[r*4+2]=a0*B[2]+a1*B[6]+a2*B[10];
    O[r*4+3]=a0*B[3]+a1*B[7]+a2*B[11]+a3;
  }
}

static __device__ __forceinline__ void load12(const float4* b4, int idx, float* a){
  float4 x=b4[idx*3+0], y=b4[idx*3+1], z=b4[idx*3+2];
  a[0]=x.x;a[1]=x.y;a[2]=x.z;a[3]=x.w;
  a[4]=y.x;a[5]=y.y;a[6]=y.z;a[7]=y.w;
  a[8]=z.x;a[9]=z.y;a[10]=z.z;a[11]=z.w;
}
static __device__ __forceinline__ void store12(float4* b4, int idx, const float* a){
  b4[idx*3+0]=make_float4(a[0],a[1],a[2],a[3]);
  b4[idx*3+1]=make_float4(a[4],a[5],a[6],a[7]);
  b4[idx*3+2]=make_float4(a[8],a[9],a[10],a[11]);
}

/* Wave-parallel doubling scan for one 64-node segment (proven r2-r13). */
static __device__ __forceinline__ void wave_scan(
    int w, int lane,
    const float* __restrict__ masked, const float4* __restrict__ base4,
    const int* __restrict__ parents,
    float G[12], int& pk)
{
  int i0 = w*SEGLEN;
  int i = i0 + lane;
  if(i == 0 || i >= NN1){
    set_ident(G); pk = 0xFF;
  } else {
    float4 b = base4[i];
    float phi = masked[i];
    float sp,cp,st,ct;
    __sincosf(phi,&sp,&cp);
    __sincosf(b.y,&st,&ct);
    float dd = b.z;
    G[0]=cp*ct; G[1]=-sp; G[2]=cp*st; G[3]=dd*G[0];
    G[4]=sp*ct; G[5]=cp;  G[6]=sp*st; G[7]=dd*G[4];
    G[8]=-st;   G[9]=0.f; G[10]=ct;   G[11]=dd*G[8];
    int rel = parents[i] - i0;
    pk = (rel >= 0) ? rel : (((rel+4)<<8) | 0xFF);
  }
  #pragma unroll
  for(int step=0; step<6; ++step){
    int ptr = pk & 0xFF;
    bool act = (ptr != 0xFF);
    int src = act ? ptr : lane;
    float g2[12];
    #pragma unroll
    for(int q=0;q<12;q++) g2[q] = __shfl(G[q], src, 64);
    int pk2 = __shfl(pk, src, 64);
    float ng[12];
    compose(g2, G, ng);
    #pragma unroll
    for(int q=0;q<12;q++) G[q] = act ? ng[q] : G[q];
    pk = act ? pk2 : pk;
  }
}

/* fk1: level-0 wave scans -> NT (t_rel, tag), kinInv scatter, segment links;
   zero d_out. */
__global__ __launch_bounds__(1024) void fk1(
    const float* __restrict__ masked, const float4* __restrict__ base4,
    const int* __restrict__ parents, const int* __restrict__ kin,
    float4* __restrict__ L1G, int* __restrict__ L1E,
    float4* __restrict__ NT, int* __restrict__ kinInv,
    float* __restrict__ out)
{
  if(blockIdx.x==0 && threadIdx.x < PP) out[threadIdx.x] = 0.f;
  int w = blockIdx.x*16 + (threadIdx.x>>6);
  if(w >= NSEG) return;
  int lane = threadIdx.x & 63;
  int i = w*SEGLEN + lane;
  if(i > 0 && i < NN1) kinInv[kin[i-1]] = i-1;  /* fire-and-forget 4B scatter */
  float G[12]; int pk;
  wave_scan(w, lane, masked, base4, parents, G, pk);
  int tag = (pk>>8)&3;
  if(i < NN1){
    NT[i] = make_float4(G[3], G[7], G[11], __int_as_float(tag));
  }
  if(lane >= 60){
    int j = lane - 60;
    store12(L1G, w*4+j, G);
    L1E[w*4+j] = tag;
  }
}

/* fk2: one wave per chunk of 64 segments; Hillis-Steele doubling over the
   window monoid (4 transforms + 4 entry tags per lane). Proven r10-r13. */
__global__ __launch_bounds__(64) void fk2(
    const float4* __restrict__ L1G, const int* __restrict__ L1E,
    float4* __restrict__ PREG, int* __restrict__ PREE,
    float4* __restrict__ CLG, int* __restrict__ CLE)
{
  int g = blockIdx.x;           /* chunk id 0..NCHK-1 */
  int j = threadIdx.x;          /* lane = local segment index */
  int s0 = g*CHUNK;
  int ns = min(CHUNK, NSEG - s0);
  int sj = s0 + min(j, ns-1);   /* clamped load index */

  float A[4][12]; int at[4];
  #pragma unroll
  for(int t=0;t<4;t++){
    load12(L1G, sj*4+t, A[t]);
    at[t] = L1E[sj*4+t];
  }
  if(j >= ns){
    #pragma unroll
    for(int t=0;t<4;t++){ set_ident(A[t]); at[t]=t; }
  }

  #pragma unroll
  for(int step=0; step<6; ++step){
    int d = 1<<step;
    int src = (j >= d) ? (j - d) : j;
    float f[4][12]; int ft[4];
    #pragma unroll
    for(int t=0;t<4;t++){
      #pragma unroll
      for(int q=0;q<12;q++) f[t][q] = __shfl(A[t][q], src, 64);
      ft[t] = __shfl(at[t], src, 64);
    }
    bool act = (j >= d) && (j < ns);
    float nA[4][12]; int nt[4];
    #pragma unroll
    for(int t=0;t<4;t++){
      int tt = at[t];
      float sel[12];
      #pragma unroll
      for(int q=0;q<12;q++){
        float v01 = (tt&1) ? f[1][q] : f[0][q];
        float v23 = (tt&1) ? f[3][q] : f[2][q];
        sel[q] = (tt&2) ? v23 : v01;
      }
      compose(sel, A[t], nA[t]);
      int t01 = (tt&1) ? ft[1] : ft[0];
      int t23 = (tt&1) ? ft[3] : ft[2];
      nt[t] = (tt&2) ? t23 : t01;
    }
    #pragma unroll
    for(int t=0;t<4;t++){
      #pragma unroll
      for(int q=0;q<12;q++) A[t][q] = act ? nA[t][q] : A[t][q];
      at[t] = act ? nt[t] : at[t];
    }
  }

  /* writes: exclusive prefix = scanned value of lane j -> segment j+1 */
  if(j == 0){
    float I[12]; set_ident(I);
    #pragma unroll
    for(int t=0;t<4;t++){
      store12(PREG, s0*4+t, I);
      PREE[s0*4+t] = t;
    }
  }
  if(j < ns-1){
    #pragma unroll
    for(int t=0;t<4;t++){
      store12(PREG, (s0+j+1)*4+t, A[t]);
      PREE[(s0+j+1)*4+t] = at[t];
    }
  }
  if(j == ns-1){
    #pragma unroll
    for(int t=0;t<4;t++){
      store12(CLG, g*4+t, A[t]);
      CLE[g*4+t] = at[t];
    }
  }
}

/* fk34: per-block redundant chunk-link doubling in LDS (proven r13), then
   apply + COALESCED position write POS[i-1] (kin scatter removed). */
__global__ __launch_bounds__(1024) void fk34(
    const float4* __restrict__ NT,
    const float4* __restrict__ PREG, const int* __restrict__ PREE,
    const float4* __restrict__ CLG, const int* __restrict__ CLE,
    float4* __restrict__ POS)
{
  __shared__ float Lg[NE*12];    /* 24.8 KB */
  __shared__ int   Le[NE];
  float4* Lg4 = (float4*)Lg;
  int tid = threadIdx.x;

  /* ---- doubling over chunk links (identical math to r12 fk3) ---- */
  if(tid < NE){
    float a[12]; load12(CLG, tid, a);
    Lg4[tid*3+0]=make_float4(a[0],a[1],a[2],a[3]);
    Lg4[tid*3+1]=make_float4(a[4],a[5],a[6],a[7]);
    Lg4[tid*3+2]=make_float4(a[8],a[9],a[10],a[11]);
    Le[tid]=CLE[tid];
  }
  __syncthreads();
  for(int d=1; d<NCHK; d<<=1){
    float ng[12]; int ne2=0;
    bool doit = (tid<NE) && ((tid>>2)>=d);
    if(doit){
      int myE = Le[tid];
      int pe = ((tid>>2)-d)*4 + myE;
      float own[12], pg[12];
      load12(Lg4, tid, own);
      load12(Lg4, pe, pg);
      compose(pg, own, ng);
      ne2 = Le[pe];
    }
    __syncthreads();
    if(doit){
      Lg4[tid*3+0]=make_float4(ng[0],ng[1],ng[2],ng[3]);
      Lg4[tid*3+1]=make_float4(ng[4],ng[5],ng[6],ng[7]);
      Lg4[tid*3+2]=make_float4(ng[8],ng[9],ng[10],ng[11]);
      Le[tid]=ne2;
    }
    __syncthreads();
  }

  /* ---- apply + coalesced store ---- */
  int w = blockIdx.x*16 + (tid>>6);
  if(w >= NSEG) return;
  int lane = tid & 63;
  int i = w*SEGLEN + lane;
  if(i == 0 || i >= NN1) return;
  float4 nt = NT[i];
  int tag = __float_as_int(nt.w) & 3;
  int c = w >> 6;                /* CHUNK = 64 */
  int e = PREE[w*4+tag];
  float bg[12], pg[12], A[12];
  if(c == 0){ set_ident(bg); }
  else { load12(Lg4, (c-1)*4+e, bg); }   /* boundary = scan result of chunk c-1 */
  load12(PREG, w*4+tag, pg);
  compose(bg, pg, A);
  float x = A[0]*nt.x + A[1]*nt.y + A[2]*nt.z  + A[3];
  float y = A[4]*nt.x + A[5]*nt.y + A[6]*nt.z  + A[7];
  float z = A[8]*nt.x + A[9]*nt.y + A[10]*nt.z + A[11];
  POS[i-1] = make_float4(x, y, z, 0.f);
}

/* fk5: bond energy via single-indirection gather. Block = 1024 bonds, one
   pose per block (1024 | 65536). Positions staged in LDS. */
__global__ __launch_bounds__(1024) void fk5(
    const float4* __restrict__ POS, const int* __restrict__ kinInv,
    const float* __restrict__ bw, float* __restrict__ out)
{
  __shared__ float sx[1025], sy[1025], sz[1025];
  __shared__ float red[16];
  int tid = threadIdx.x;
  int base = blockIdx.x * 1024;
  int r = base + tid;
  float4 p0 = POS[kinInv[r]];
  sx[tid]=p0.x; sy[tid]=p0.y; sz[tid]=p0.z;
  if(tid == 0 && base + 1024 < N_TOT){
    float4 p1 = POS[kinInv[base + 1024]];
    sx[1024]=p1.x; sy[1024]=p1.y; sz[1024]=p1.z;
  }
  __syncthreads();
  int a = r & (AA-1);
  float sum = 0.f;
  if(a != AA-1){
    float dx = sx[tid+1]-sx[tid];
    float dy = sy[tid+1]-sy[tid];
    float dz = sz[tid+1]-sz[tid];
    sum = bw[(r>>16)*(AA-1) + a]*(dx*dx+dy*dy+dz*dz);
  }
  #pragma unroll
  for(int off=32; off>0; off>>=1) sum += __shfl_down(sum, off, 64);
  int lane = tid & 63, wid = tid >> 6;
  if(lane==0) red[wid]=sum;
  __syncthreads();
  if(tid==0){
    float tot=0.f;
    #pragma unroll
    for(int q=0;q<16;q++) tot += red[q];
    atomicAdd(&out[base>>16], tot);
  }
}

extern "C" void kernel_launch(void* const* d_in, const int* in_sizes, int n_in,
                              void* d_out, int out_size, void* d_ws, size_t ws_size,
                              hipStream_t stream)
{
  const float*  masked  = (const float*)d_in[0];
  const float4* base4   = (const float4*)d_in[1];
  /* d_in[2] pose_coords unused: kin_id is a full permutation */
  const float*  bw      = (const float*)d_in[3];
  const int*    parents = (const int*)d_in[4];
  const int*    kin     = (const int*)d_in[5];

  float* ws = (float*)d_ws;
  float4* POS   = (float4*)(ws + OFF_POS);
  float4* NT    = (float4*)(ws + OFF_NT);
  float4* L1G   = (float4*)(ws + OFF_L1G);
  int*    L1E   = (int*)(ws + OFF_L1E);
  float4* PREG  = (float4*)(ws + OFF_PREG);
  int*    PREE  = (int*)(ws + OFF_PREE);
  float4* CLG   = (float4*)(ws + OFF_CLG);
  int*    CLE   = (int*)(ws + OFF_CLE);
  int*    kinInv= (int*)(ws + OFF_KINV);
  float*  out   = (float*)d_out;

  int nblk = (NSEG + 15) / 16;   /* 513 blocks of 1024 threads (16 waves) */
  fk1<<<nblk, 1024, 0, stream>>>(masked, base4, parents, kin, L1G, L1E, NT, kinInv, out);
  fk2<<<NCHK, 64, 0, stream>>>(L1G, L1E, PREG, PREE, CLG, CLE);
  fk34<<<nblk, 1024, 0, stream>>>(NT, PREG, PREE, CLG, CLE, POS);
  fk5<<<N_TOT/1024, 1024, 0, stream>>>(POS, kinInv, bw, out);
}

// Round 15
// 47.844 us; speedup vs baseline: 1.1728x; 1.1728x over previous
//
#include <hip/hip_runtime.h>

#define N_TOT  524288
#define NN1    524289
#define PP     8
#define AA     65536
#define SEGLEN 64
#define NSEG   8193      /* ceil(NN1/64) */
#define CHUNK  64        /* segments per chunk (full wave) */
#define NCHK   129       /* ceil(NSEG/64) */
#define NE     (NCHK*4)  /* 516 link slots */

/* workspace offsets, in floats (all float4-aligned) */
#define OFF_COORDS 0          /* float4[524288] = 2097152 floats */
#define OFF_NT   2097152      /* float4[NN1]    = 2097156 floats */
#define OFF_L1G  4194308      /* NSEG*48 = 393264 */
#define OFF_L1E  4587572      /* NSEG*4 ints */
#define OFF_PREG 4620344      /* NSEG*48 */
#define OFF_PREE 5013608      /* NSEG*4 ints */
#define OFF_CLG  5046380      /* NE*12 = 6192 */
#define OFF_CLE  5052572      /* NE ints */

static __device__ __forceinline__ void set_ident(float* a){
  a[0]=1.f;a[1]=0.f;a[2]=0.f;a[3]=0.f;
  a[4]=0.f;a[5]=1.f;a[6]=0.f;a[7]=0.f;
  a[8]=0.f;a[9]=0.f;a[10]=1.f;a[11]=0.f;
}

/* O = A @ B (3x4 affine, row-major) */
static __device__ __forceinline__ void compose(const float* Aa, const float* B, float* O){
  #pragma unroll
  for(int r=0;r<3;r++){
    float a0=Aa[r*4+0],a1=Aa[r*4+1],a2=Aa[r*4+2],a3=Aa[r*4+3];
    O[r*4+0]=a0*B[0]+a1*B[4]+a2*B[8];
    O[r*4+1]=a0*B[1]+a1*B[5]+a2*B[9];
    O[r*4+2]=a0*B[2]+a1*B[6]+a2*B[10];
    O[r*4+3]=a0*B[3]+a1*B[7]+a2*B[11]+a3;
  }
}

static __device__ __forceinline__ void load12(const float4* b4, int idx, float* a){
  float4 x=b4[idx*3+0], y=b4[idx*3+1], z=b4[idx*3+2];
  a[0]=x.x;a[1]=x.y;a[2]=x.z;a[3]=x.w;
  a[4]=y.x;a[5]=y.y;a[6]=y.z;a[7]=y.w;
  a[8]=z.x;a[9]=z.y;a[10]=z.z;a[11]=z.w;
}
static __device__ __forceinline__ void store12(float4* b4, int idx, const float* a){
  b4[idx*3+0]=make_float4(a[0],a[1],a[2],a[3]);
  b4[idx*3+1]=make_float4(a[4],a[5],a[6],a[7]);
  b4[idx*3+2]=make_float4(a[8],a[9],a[10],a[11]);
}

/* Wave-parallel doubling scan for one 64-node segment (proven r2-r14).
   Trig: native __sinf/__cosf (v_sin/v_cos) instead of __sincosf. */
static __device__ __forceinline__ void wave_scan(
    int w, int lane,
    const float* __restrict__ masked, const float4* __restrict__ base4,
    const int* __restrict__ parents,
    float G[12], int& pk)
{
  int i0 = w*SEGLEN;
  int i = i0 + lane;
  if(i == 0 || i >= NN1){
    set_ident(G); pk = 0xFF;
  } else {
    float4 b = base4[i];
    float phi = masked[i];
    float sp = __sinf(phi), cp = __cosf(phi);
    float st = __sinf(b.y), ct = __cosf(b.y);
    float dd = b.z;
    G[0]=cp*ct; G[1]=-sp; G[2]=cp*st; G[3]=dd*G[0];
    G[4]=sp*ct; G[5]=cp;  G[6]=sp*st; G[7]=dd*G[4];
    G[8]=-st;   G[9]=0.f; G[10]=ct;   G[11]=dd*G[8];
    int rel = parents[i] - i0;
    pk = (rel >= 0) ? rel : (((rel+4)<<8) | 0xFF);
  }
  #pragma unroll
  for(int step=0; step<6; ++step){
    int ptr = pk & 0xFF;
    bool act = (ptr != 0xFF);
    int src = act ? ptr : lane;
    float g2[12];
    #pragma unroll
    for(int q=0;q<12;q++) g2[q] = __shfl(G[q], src, 64);
    int pk2 = __shfl(pk, src, 64);
    float ng[12];
    compose(g2, G, ng);
    #pragma unroll
    for(int q=0;q<12;q++) G[q] = act ? ng[q] : G[q];
    pk = act ? pk2 : pk;
  }
}

/* fk1: level-0 wave scans -> NT (t_rel, tag), segment links; zero d_out. */
__global__ __launch_bounds__(1024) void fk1(
    const float* __restrict__ masked, const float4* __restrict__ base4,
    const int* __restrict__ parents,
    float4* __restrict__ L1G, int* __restrict__ L1E,
    float4* __restrict__ NT, float* __restrict__ out)
{
  if(blockIdx.x==0 && threadIdx.x < PP) out[threadIdx.x] = 0.f;
  int w = blockIdx.x*16 + (threadIdx.x>>6);
  if(w >= NSEG) return;
  int lane = threadIdx.x & 63;
  float G[12]; int pk;
  wave_scan(w, lane, masked, base4, parents, G, pk);
  int i = w*SEGLEN + lane;
  int tag = (pk>>8)&3;
  if(i < NN1){
    NT[i] = make_float4(G[3], G[7], G[11], __int_as_float(tag));
  }
  if(lane >= 60){
    int j = lane - 60;
    store12(L1G, w*4+j, G);
    L1E[w*4+j] = tag;
  }
}

/* fk2: one wave per chunk of 64 segments; Hillis-Steele doubling over the
   window monoid (4 transforms + 4 entry tags per lane). Proven r10-r14. */
__global__ __launch_bounds__(64) void fk2(
    const float4* __restrict__ L1G, const int* __restrict__ L1E,
    float4* __restrict__ PREG, int* __restrict__ PREE,
    float4* __restrict__ CLG, int* __restrict__ CLE)
{
  int g = blockIdx.x;           /* chunk id 0..NCHK-1 */
  int j = threadIdx.x;          /* lane = local segment index */
  int s0 = g*CHUNK;
  int ns = min(CHUNK, NSEG - s0);
  int sj = s0 + min(j, ns-1);   /* clamped load index */

  float A[4][12]; int at[4];
  #pragma unroll
  for(int t=0;t<4;t++){
    load12(L1G, sj*4+t, A[t]);
    at[t] = L1E[sj*4+t];
  }
  if(j >= ns){
    #pragma unroll
    for(int t=0;t<4;t++){ set_ident(A[t]); at[t]=t; }
  }

  #pragma unroll
  for(int step=0; step<6; ++step){
    int d = 1<<step;
    int src = (j >= d) ? (j - d) : j;
    float f[4][12]; int ft[4];
    #pragma unroll
    for(int t=0;t<4;t++){
      #pragma unroll
      for(int q=0;q<12;q++) f[t][q] = __shfl(A[t][q], src, 64);
      ft[t] = __shfl(at[t], src, 64);
    }
    bool act = (j >= d) && (j < ns);
    float nA[4][12]; int nt[4];
    #pragma unroll
    for(int t=0;t<4;t++){
      int tt = at[t];
      float sel[12];
      #pragma unroll
      for(int q=0;q<12;q++){
        float v01 = (tt&1) ? f[1][q] : f[0][q];
        float v23 = (tt&1) ? f[3][q] : f[2][q];
        sel[q] = (tt&2) ? v23 : v01;
      }
      compose(sel, A[t], nA[t]);
      int t01 = (tt&1) ? ft[1] : ft[0];
      int t23 = (tt&1) ? ft[3] : ft[2];
      nt[t] = (tt&2) ? t23 : t01;
    }
    #pragma unroll
    for(int t=0;t<4;t++){
      #pragma unroll
      for(int q=0;q<12;q++) A[t][q] = act ? nA[t][q] : A[t][q];
      at[t] = act ? nt[t] : at[t];
    }
  }

  /* writes: exclusive prefix = scanned value of lane j -> segment j+1 */
  if(j == 0){
    float I[12]; set_ident(I);
    #pragma unroll
    for(int t=0;t<4;t++){
      store12(PREG, s0*4+t, I);
      PREE[s0*4+t] = t;
    }
  }
  if(j < ns-1){
    #pragma unroll
    for(int t=0;t<4;t++){
      store12(PREG, (s0+j+1)*4+t, A[t]);
      PREE[(s0+j+1)*4+t] = at[t];
    }
  }
  if(j == ns-1){
    #pragma unroll
    for(int t=0;t<4;t++){
      store12(CLG, g*4+t, A[t]);
      CLE[g*4+t] = at[t];
    }
  }
}

/* fk34: per-block redundant chunk-link doubling in LDS (proven r13), then
   the proven apply + scatter-store (r13 optimum; both gather variants
   falsified r11/r14). */
__global__ __launch_bounds__(1024) void fk34(
    const int* __restrict__ kin, const float4* __restrict__ NT,
    const float4* __restrict__ PREG, const int* __restrict__ PREE,
    const float4* __restrict__ CLG, const int* __restrict__ CLE,
    float4* __restrict__ coords)
{
  __shared__ float Lg[NE*12];    /* 24.8 KB */
  __shared__ int   Le[NE];
  float4* Lg4 = (float4*)Lg;
  int tid = threadIdx.x;

  /* ---- doubling over chunk links ---- */
  if(tid < NE){
    float a[12]; load12(CLG, tid, a);
    Lg4[tid*3+0]=make_float4(a[0],a[1],a[2],a[3]);
    Lg4[tid*3+1]=make_float4(a[4],a[5],a[6],a[7]);
    Lg4[tid*3+2]=make_float4(a[8],a[9],a[10],a[11]);
    Le[tid]=CLE[tid];
  }
  __syncthreads();
  for(int d=1; d<NCHK; d<<=1){
    float ng[12]; int ne2=0;
    bool doit = (tid<NE) && ((tid>>2)>=d);
    if(doit){
      int myE = Le[tid];
      int pe = ((tid>>2)-d)*4 + myE;
      float own[12], pg[12];
      load12(Lg4, tid, own);
      load12(Lg4, pe, pg);
      compose(pg, own, ng);
      ne2 = Le[pe];
    }
    __syncthreads();
    if(doit){
      Lg4[tid*3+0]=make_float4(ng[0],ng[1],ng[2],ng[3]);
      Lg4[tid*3+1]=make_float4(ng[4],ng[5],ng[6],ng[7]);
      Lg4[tid*3+2]=make_float4(ng[8],ng[9],ng[10],ng[11]);
      Le[tid]=ne2;
    }
    __syncthreads();
  }

  /* ---- apply + scatter ---- */
  int w = blockIdx.x*16 + (tid>>6);
  if(w >= NSEG) return;
  int lane = tid & 63;
  int i = w*SEGLEN + lane;
  if(i == 0 || i >= NN1) return;
  float4 nt = NT[i];
  int tag = __float_as_int(nt.w) & 3;
  int c = w >> 6;                /* CHUNK = 64 */
  int e = PREE[w*4+tag];
  float bg[12], pg[12], A[12];
  if(c == 0){ set_ident(bg); }
  else { load12(Lg4, (c-1)*4+e, bg); }   /* boundary = scan result of chunk c-1 */
  load12(PREG, w*4+tag, pg);
  compose(bg, pg, A);
  float x = A[0]*nt.x + A[1]*nt.y + A[2]*nt.z  + A[3];
  float y = A[4]*nt.x + A[5]*nt.y + A[6]*nt.z  + A[7];
  float z = A[8]*nt.x + A[9]*nt.y + A[10]*nt.z + A[11];
  coords[kin[i-1]] = make_float4(x, y, z, 0.f);
}

/* fk5: bond energy; 32 blocks/pose, shfl+LDS reduce, atomicAdd (proven r2-r13) */
__global__ void fk5(const float4* __restrict__ coords, const float* __restrict__ bw,
                    float* __restrict__ out)
{
  int p = blockIdx.x >> 5;
  int sub = blockIdx.x & 31;
  int a0 = sub * 2048;
  int aend = min(a0 + 2048, AA - 1);
  float sum = 0.f;
  for(int a = a0 + (int)threadIdx.x; a < aend; a += 256){
    int r = p*AA + a;
    float4 c0 = coords[r], c1 = coords[r+1];
    float dx = c1.x-c0.x, dy = c1.y-c0.y, dz = c1.z-c0.z;
    sum += bw[p*(AA-1)+a]*(dx*dx+dy*dy+dz*dz);
  }
  #pragma unroll
  for(int off=32;off>0;off>>=1) sum += __shfl_down(sum, off, 64);
  __shared__ float red[4];
  int lane = threadIdx.x & 63, wid = threadIdx.x >> 6;
  if(lane==0) red[wid]=sum;
  __syncthreads();
  if(threadIdx.x==0){
    float tot = red[0]+red[1]+red[2]+red[3];
    atomicAdd(&out[p], tot);
  }
}

extern "C" void kernel_launch(void* const* d_in, const int* in_sizes, int n_in,
                              void* d_out, int out_size, void* d_ws, size_t ws_size,
                              hipStream_t stream)
{
  const float*  masked  = (const float*)d_in[0];
  const float4* base4   = (const float4*)d_in[1];
  /* d_in[2] pose_coords unused: kin_id is a full permutation */
  const float*  bw      = (const float*)d_in[3];
  const int*    parents = (const int*)d_in[4];
  const int*    kin     = (const int*)d_in[5];

  float* ws = (float*)d_ws;
  float4* coords = (float4*)(ws + OFF_COORDS);
  float4* NT   = (float4*)(ws + OFF_NT);
  float4* L1G  = (float4*)(ws + OFF_L1G);
  int*    L1E  = (int*)(ws + OFF_L1E);
  float4* PREG = (float4*)(ws + OFF_PREG);
  int*    PREE = (int*)(ws + OFF_PREE);
  float4* CLG  = (float4*)(ws + OFF_CLG);
  int*    CLE  = (int*)(ws + OFF_CLE);
  float*  out  = (float*)d_out;

  int nblk = (NSEG + 15) / 16;   /* 513 blocks of 1024 threads (16 waves) */
  fk1<<<nblk, 1024, 0, stream>>>(masked, base4, parents, L1G, L1E, NT, out);
  fk2<<<NCHK, 64, 0, stream>>>(L1G, L1E, PREG, PREE, CLG, CLE);
  fk34<<<nblk, 1024, 0, stream>>>(kin, NT, PREG, PREE, CLG, CLE, coords);
  fk5<<<PP*32, 256, 0, stream>>>(coords, bw, out);
}